// Round 6
// baseline (259.590 us; speedup 1.0000x reference)
//
#include <hip/hip_runtime.h>
#include <hip/hip_cooperative_groups.h>

namespace cg = cooperative_groups;

#define D_FEAT 128
#define BLOCK  256

// Fused single-dispatch edge-softmax (cooperative launch):
//   phase 0: zero seg_sum                          -> grid.sync()
//   phase 1: 8-lane groups: p = exp(exp(-0.01*L1(feats[src],feats[dst])));
//            out[e] = p; atomicAdd(seg_sum+dst, p) -> grid.sync()
//   phase 2: out[e] /= seg_sum[dst[e]]  (float4-vectorized)
// The reference's seg_max pass is dropped: softmax is shift-invariant and
// e = exp(-0.01*L1) is in (0,1], so exp(e) <= 2.72 -- no overflow possible.
__global__ void __launch_bounds__(BLOCK, 4)
fused_edge_softmax(const float* __restrict__ feats,
                   const int* __restrict__ src,
                   const int* __restrict__ dst,
                   float* __restrict__ seg_sum,
                   float* __restrict__ out,
                   int E, int N) {
    cg::grid_group grid = cg::this_grid();

    int tid  = blockIdx.x * blockDim.x + threadIdx.x;
    int nthr = gridDim.x * blockDim.x;

    // phase 0: zero seg_sum (d_ws is poisoned once; must zero every call)
    for (int i = tid; i < N; i += nthr) seg_sum[i] = 0.0f;

    grid.sync();

    // phase 1: 8 lanes per edge, grid-stride over edges
    int sl      = threadIdx.x & 7;
    int group   = tid >> 3;
    int ngroups = nthr >> 3;
    for (int e = group; e < E; e += ngroups) {
        int s = src[e];
        int d = dst[e];
        const float4* fa = (const float4*)(feats + (size_t)s * D_FEAT);
        const float4* fb = (const float4*)(feats + (size_t)d * D_FEAT);
        float4 a0 = fa[sl];
        float4 a1 = fa[sl + 8];
        float4 a2 = fa[sl + 16];
        float4 a3 = fa[sl + 24];
        float4 b0 = fb[sl];
        float4 b1 = fb[sl + 8];
        float4 b2 = fb[sl + 16];
        float4 b3 = fb[sl + 24];

        float sum = fabsf(a0.x - b0.x) + fabsf(a0.y - b0.y)
                  + fabsf(a0.z - b0.z) + fabsf(a0.w - b0.w)
                  + fabsf(a1.x - b1.x) + fabsf(a1.y - b1.y)
                  + fabsf(a1.z - b1.z) + fabsf(a1.w - b1.w)
                  + fabsf(a2.x - b2.x) + fabsf(a2.y - b2.y)
                  + fabsf(a2.z - b2.z) + fabsf(a2.w - b2.w)
                  + fabsf(a3.x - b3.x) + fabsf(a3.y - b3.y)
                  + fabsf(a3.z - b3.z) + fabsf(a3.w - b3.w);

        #pragma unroll
        for (int off = 4; off >= 1; off >>= 1)
            sum += __shfl_xor(sum, off, 64);

        if (sl == 0) {
            float p = expf(expf(-0.01f * sum));
            out[e] = p;
            atomicAdd(seg_sum + d, p);
        }
    }

    grid.sync();

    // phase 2: normalize, float4-vectorized (E % 4 handled by scalar tail)
    int E4 = E >> 2;
    for (int i = tid; i < E4; i += nthr) {
        float4 p = ((const float4*)out)[i];
        int4   d = ((const int4*)dst)[i];
        p.x /= seg_sum[d.x];
        p.y /= seg_sum[d.y];
        p.z /= seg_sum[d.z];
        p.w /= seg_sum[d.w];
        ((float4*)out)[i] = p;
    }
    for (int e = (E4 << 2) + tid; e < E; e += nthr)
        out[e] = out[e] / seg_sum[dst[e]];
}

// ---------- fallback (non-cooperative) path ----------
__global__ void fb_eval(const float* __restrict__ feats,
                        const int* __restrict__ src,
                        const int* __restrict__ dst,
                        float* __restrict__ seg_sum,
                        float* __restrict__ out, int E) {
    int gtid = blockIdx.x * blockDim.x + threadIdx.x;
    int edge = gtid >> 3;
    int sl   = threadIdx.x & 7;
    if (edge >= E) return;
    int s = src[edge], d = dst[edge];
    const float4* fa = (const float4*)(feats + (size_t)s * D_FEAT);
    const float4* fb = (const float4*)(feats + (size_t)d * D_FEAT);
    float sum = 0.f;
    #pragma unroll
    for (int k = 0; k < 4; ++k) {
        float4 a = fa[sl + 8 * k], b = fb[sl + 8 * k];
        sum += fabsf(a.x - b.x) + fabsf(a.y - b.y)
             + fabsf(a.z - b.z) + fabsf(a.w - b.w);
    }
    #pragma unroll
    for (int off = 4; off >= 1; off >>= 1) sum += __shfl_xor(sum, off, 64);
    if (sl == 0) {
        float p = expf(expf(-0.01f * sum));
        out[edge] = p;
        atomicAdd(seg_sum + d, p);
    }
}
__global__ void fb_div(const int* __restrict__ dst,
                       const float* __restrict__ seg_sum,
                       float* __restrict__ out, int E) {
    int e = blockIdx.x * blockDim.x + threadIdx.x;
    if (e < E) out[e] = out[e] / seg_sum[dst[e]];
}

extern "C" void kernel_launch(void* const* d_in, const int* in_sizes, int n_in,
                              void* d_out, int out_size, void* d_ws, size_t ws_size,
                              hipStream_t stream) {
    const float* feats = (const float*)d_in[0];
    const int*   eidx  = (const int*)d_in[1];

    const int E = in_sizes[1] / 2;          // 320000
    const int N = in_sizes[0] / D_FEAT;     // 10000

    const int* src = eidx;
    const int* dst = eidx + E;

    float* seg_sum = (float*)d_ws;          // [N]
    float* out     = (float*)d_out;         // [E]

    // Size the cooperative grid from the occupancy API (host-side, capture-
    // safe, deterministic) so the launch can never exceed co-residency.
    int dev = 0;
    hipGetDevice(&dev);
    int numCU = 0;
    hipDeviceGetAttribute(&numCU, hipDeviceAttributeMultiprocessorCount, dev);
    int blocksPerCU = 0;
    hipOccupancyMaxActiveBlocksPerMultiprocessor(
        &blocksPerCU, reinterpret_cast<const void*>(fused_edge_softmax),
        BLOCK, 0);

    int grid = numCU * blocksPerCU;
    int needed = (E + (BLOCK / 8) - 1) / (BLOCK / 8);  // 1 pass over edges
    if (grid > needed) grid = needed;

    if (grid >= 1 && blocksPerCU >= 1) {
        void* args[] = {(void*)&feats, (void*)&src, (void*)&dst,
                        (void*)&seg_sum, (void*)&out, (void*)&E, (void*)&N};
        hipLaunchCooperativeKernel(reinterpret_cast<void*>(fused_edge_softmax),
                                   dim3(grid), dim3(BLOCK), args, 0, stream);
    } else {
        hipMemsetAsync(seg_sum, 0, (size_t)N * sizeof(float), stream);
        fb_eval<<<dim3((E * 8 + BLOCK - 1) / BLOCK), dim3(BLOCK), 0, stream>>>(
            feats, src, dst, seg_sum, out, E);
        fb_div<<<dim3((E + BLOCK - 1) / BLOCK), dim3(BLOCK), 0, stream>>>(
            dst, seg_sum, out, E);
    }
}

// Round 7
// 41.230 us; speedup vs baseline: 6.2962x; 6.2962x over previous
//
#include <hip/hip_runtime.h>

#define D_FEAT 128
#define BLOCK  256
#define NITER  10                 // static register-carried passes per thread
#define GPB    (BLOCK / 8)        // 8-lane groups per block = 32

// ---------------- software global barrier (all blocks co-resident) ---------
// Monotone epoch counter, zeroed by an 8B memset before each launch.
// Each block's thread 0 arrives (agent-scope ACQ_REL add) and spins on an
// agent-scope ACQUIRE load until the epoch completes. Works for repeated
// barriers: epoch k completes when cnt reaches (k+1)*nblocks.
__device__ inline void global_barrier(unsigned* cnt) {
    __syncthreads();
    if (threadIdx.x == 0) {
        unsigned old = __hip_atomic_fetch_add(cnt, 1u, __ATOMIC_ACQ_REL,
                                              __HIP_MEMORY_SCOPE_AGENT);
        unsigned target = (old / gridDim.x + 1u) * gridDim.x;
        while (__hip_atomic_load(cnt, __ATOMIC_ACQUIRE,
                                 __HIP_MEMORY_SCOPE_AGENT) < target) {
            __builtin_amdgcn_s_sleep(2);
        }
    }
    __syncthreads();
}

// Fused edge-softmax, single dispatch (non-cooperative, software barrier):
//   phase 0: zero seg_sum (agent-scope atomic stores)   -> barrier
//   phase 1: 8-lane groups: p = exp(exp(-0.01*L1));
//            agent-scope atomicAdd(seg_sum+d, p); p,d kept in registers
//                                                       -> barrier
//   phase 2: out[e] = p / seg_sum[d]   (register-carried, no re-reads)
// seg_max pass dropped: softmax is shift-invariant and e = exp(-0.01*L1)
// is in (0,1], so exp(e) <= 2.72 -- no overflow possible.
__global__ void __launch_bounds__(BLOCK, 4)
fused_edge_softmax(const float* __restrict__ feats,
                   const int* __restrict__ src,
                   const int* __restrict__ dst,
                   unsigned* __restrict__ cnt,
                   float* __restrict__ seg_sum,
                   float* __restrict__ out,
                   int E, int N) {
    int tid  = blockIdx.x * blockDim.x + threadIdx.x;
    int nthr = gridDim.x * blockDim.x;

    // phase 0: zero seg_sum at the coherence point (agent-scope stores)
    for (int i = tid; i < N; i += nthr)
        __hip_atomic_store(seg_sum + i, 0.0f, __ATOMIC_RELAXED,
                           __HIP_MEMORY_SCOPE_AGENT);

    global_barrier(cnt);

    // phase 1: 8 lanes per edge, NITER statically-unrolled passes
    int sl      = threadIdx.x & 7;
    int group   = tid >> 3;
    int ngroups = nthr >> 3;

    float p_r[NITER];
    int   d_r[NITER];
    #pragma unroll
    for (int it = 0; it < NITER; ++it) {
        p_r[it] = 0.0f;
        d_r[it] = -1;
        int e = it * ngroups + group;
        if (e < E) {
            int s = src[e];
            int d = dst[e];
            const float4* fa = (const float4*)(feats + (size_t)s * D_FEAT);
            const float4* fb = (const float4*)(feats + (size_t)d * D_FEAT);
            float4 a0 = fa[sl];
            float4 a1 = fa[sl + 8];
            float4 a2 = fa[sl + 16];
            float4 a3 = fa[sl + 24];
            float4 b0 = fb[sl];
            float4 b1 = fb[sl + 8];
            float4 b2 = fb[sl + 16];
            float4 b3 = fb[sl + 24];

            float sum = fabsf(a0.x - b0.x) + fabsf(a0.y - b0.y)
                      + fabsf(a0.z - b0.z) + fabsf(a0.w - b0.w)
                      + fabsf(a1.x - b1.x) + fabsf(a1.y - b1.y)
                      + fabsf(a1.z - b1.z) + fabsf(a1.w - b1.w)
                      + fabsf(a2.x - b2.x) + fabsf(a2.y - b2.y)
                      + fabsf(a2.z - b2.z) + fabsf(a2.w - b2.w)
                      + fabsf(a3.x - b3.x) + fabsf(a3.y - b3.y)
                      + fabsf(a3.z - b3.z) + fabsf(a3.w - b3.w);

            #pragma unroll
            for (int off = 4; off >= 1; off >>= 1)
                sum += __shfl_xor(sum, off, 64);

            if (sl == 0) {
                float p = expf(expf(-0.01f * sum));
                p_r[it] = p;
                d_r[it] = d;
                __hip_atomic_fetch_add(seg_sum + d, p, __ATOMIC_RELAXED,
                                       __HIP_MEMORY_SCOPE_AGENT);
            }
        }
    }

    global_barrier(cnt);

    // phase 2: normalize straight from registers
    if (sl == 0) {
        #pragma unroll
        for (int it = 0; it < NITER; ++it) {
            if (d_r[it] >= 0) {
                float s = __hip_atomic_load(seg_sum + d_r[it], __ATOMIC_RELAXED,
                                            __HIP_MEMORY_SCOPE_AGENT);
                out[it * ngroups + group] = p_r[it] / s;
            }
        }
    }
}

// ---------------- fallback (proven non-cooperative 3-dispatch path) --------
__global__ void fb_eval(const float* __restrict__ feats,
                        const int* __restrict__ src,
                        const int* __restrict__ dst,
                        float* __restrict__ seg_sum,
                        float* __restrict__ out, int E) {
    int gtid = blockIdx.x * blockDim.x + threadIdx.x;
    int edge = gtid >> 3;
    int sl   = threadIdx.x & 7;
    if (edge >= E) return;
    int s = src[edge], d = dst[edge];
    const float4* fa = (const float4*)(feats + (size_t)s * D_FEAT);
    const float4* fb = (const float4*)(feats + (size_t)d * D_FEAT);
    float sum = 0.f;
    #pragma unroll
    for (int k = 0; k < 4; ++k) {
        float4 a = fa[sl + 8 * k], b = fb[sl + 8 * k];
        sum += fabsf(a.x - b.x) + fabsf(a.y - b.y)
             + fabsf(a.z - b.z) + fabsf(a.w - b.w);
    }
    #pragma unroll
    for (int off = 4; off >= 1; off >>= 1) sum += __shfl_xor(sum, off, 64);
    if (sl == 0) {
        float p = expf(expf(-0.01f * sum));
        out[edge] = p;
        atomicAdd(seg_sum + d, p);
    }
}
__global__ void fb_div(const int* __restrict__ dst,
                       const float* __restrict__ seg_sum,
                       float* __restrict__ out, int E) {
    int e = blockIdx.x * blockDim.x + threadIdx.x;
    if (e < E) out[e] = out[e] / seg_sum[dst[e]];
}

extern "C" void kernel_launch(void* const* d_in, const int* in_sizes, int n_in,
                              void* d_out, int out_size, void* d_ws, size_t ws_size,
                              hipStream_t stream) {
    const float* feats = (const float*)d_in[0];
    const int*   eidx  = (const int*)d_in[1];

    const int E = in_sizes[1] / 2;          // 320000
    const int N = in_sizes[0] / D_FEAT;     // 10000

    const int* src = eidx;
    const int* dst = eidx + E;

    unsigned* cnt     = (unsigned*)d_ws;                  // barrier counter
    float*    seg_sum = (float*)((char*)d_ws + 128);      // [N], own lines
    float*    out     = (float*)d_out;                    // [E]

    // grid so that NITER passes of (grid * GPB) groups cover E
    int grid = (E + NITER * GPB - 1) / (NITER * GPB);     // 1000 for E=320000

    // verify co-residency (host queries are capture-safe: no stream ops)
    int dev = 0;
    hipGetDevice(&dev);
    int numCU = 0;
    hipDeviceGetAttribute(&numCU, hipDeviceAttributeMultiprocessorCount, dev);
    int blocksPerCU = 0;
    hipOccupancyMaxActiveBlocksPerMultiprocessor(
        &blocksPerCU, reinterpret_cast<const void*>(fused_edge_softmax),
        BLOCK, 0);

    if (grid >= 1 && grid <= numCU * blocksPerCU) {
        hipMemsetAsync(cnt, 0, sizeof(unsigned) * 2, stream);
        fused_edge_softmax<<<dim3(grid), dim3(BLOCK), 0, stream>>>(
            feats, src, dst, cnt, seg_sum, out, E, N);
    } else {
        hipMemsetAsync(seg_sum, 0, (size_t)N * sizeof(float), stream);
        fb_eval<<<dim3((E * 8 + BLOCK - 1) / BLOCK), dim3(BLOCK), 0, stream>>>(
            feats, src, dst, seg_sum, out, E);
        fb_div<<<dim3((E + BLOCK - 1) / BLOCK), dim3(BLOCK), 0, stream>>>(
            dst, seg_sum, out, E);
    }
}

// Round 8
// 35.385 us; speedup vs baseline: 7.3361x; 1.1652x over previous
//
#include <hip/hip_runtime.h>

#define D_FEAT 128
#define PAD    16   // floats per seg_sum slot = one 64B line per node

// Kernel A: 8 lanes per edge (8 edges per wave64). Each lane loads 4x float4
// per row (8 lanes x 16B = one 128B line per load instruction).
// seg_sum is PADDED: node n lives at seg_sum[n*PAD], one 64B line per node,
// so the 320k device-scope atomicAdds spread over 10k lines (~32 RMWs/line)
// instead of 640 lines (~500 RMWs/line of cross-XCD serialization).
// The reference's seg_max pass is dropped: softmax is shift-invariant and
// e = exp(-0.01*L1) is in (0,1], so exp(e) <= 2.72 -- no overflow possible.
__global__ void edge_eval_kernel(const float* __restrict__ feats,
                                 const int* __restrict__ src,
                                 const int* __restrict__ dst,
                                 float* __restrict__ seg_sum,
                                 float* __restrict__ out,
                                 int E) {
    int gtid = blockIdx.x * blockDim.x + threadIdx.x;
    int edge = gtid >> 3;
    int sl   = threadIdx.x & 7;
    if (edge >= E) return;

    int s = src[edge];
    int d = dst[edge];

    const float4* fa = (const float4*)(feats + (size_t)s * D_FEAT);
    const float4* fb = (const float4*)(feats + (size_t)d * D_FEAT);
    float4 a0 = fa[sl];
    float4 a1 = fa[sl + 8];
    float4 a2 = fa[sl + 16];
    float4 a3 = fa[sl + 24];
    float4 b0 = fb[sl];
    float4 b1 = fb[sl + 8];
    float4 b2 = fb[sl + 16];
    float4 b3 = fb[sl + 24];

    float sum = fabsf(a0.x - b0.x) + fabsf(a0.y - b0.y)
              + fabsf(a0.z - b0.z) + fabsf(a0.w - b0.w)
              + fabsf(a1.x - b1.x) + fabsf(a1.y - b1.y)
              + fabsf(a1.z - b1.z) + fabsf(a1.w - b1.w)
              + fabsf(a2.x - b2.x) + fabsf(a2.y - b2.y)
              + fabsf(a2.z - b2.z) + fabsf(a2.w - b2.w)
              + fabsf(a3.x - b3.x) + fabsf(a3.y - b3.y)
              + fabsf(a3.z - b3.z) + fabsf(a3.w - b3.w);

    // reduce across the 8-lane group (stays within the wave)
    #pragma unroll
    for (int off = 4; off >= 1; off >>= 1)
        sum += __shfl_xor(sum, off, 64);

    if (sl == 0) {
        float p = expf(expf(-0.01f * sum));
        out[edge] = p;
        atomicAdd(seg_sum + (size_t)d * PAD, p);
    }
}

// Zero the padded seg_sum slots (only slot 0 of each line is used).
__global__ void zero_kernel(float* __restrict__ seg_sum, int N) {
    int i = blockIdx.x * blockDim.x + threadIdx.x;
    if (i < N) seg_sum[(size_t)i * PAD] = 0.0f;
}

// Kernel B: out[e] /= seg_sum[dst[e]*PAD], 4 edges per thread.
__global__ void edge_div_kernel(const int* __restrict__ dst,
                                const float* __restrict__ seg_sum,
                                float* __restrict__ out,
                                int E4) {
    int i = blockIdx.x * blockDim.x + threadIdx.x;
    if (i >= E4) return;
    float4 p = ((const float4*)out)[i];
    int4   d = ((const int4*)dst)[i];
    p.x /= seg_sum[(size_t)d.x * PAD];
    p.y /= seg_sum[(size_t)d.y * PAD];
    p.z /= seg_sum[(size_t)d.z * PAD];
    p.w /= seg_sum[(size_t)d.w * PAD];
    ((float4*)out)[i] = p;
}

// scalar tail (E % 4 != 0) — not hit for E=320000, kept for generality
__global__ void edge_div_tail_kernel(const int* __restrict__ dst,
                                     const float* __restrict__ seg_sum,
                                     float* __restrict__ out,
                                     int start, int E) {
    int e = start + blockIdx.x * blockDim.x + threadIdx.x;
    if (e >= E) return;
    out[e] = out[e] / seg_sum[(size_t)dst[e] * PAD];
}

extern "C" void kernel_launch(void* const* d_in, const int* in_sizes, int n_in,
                              void* d_out, int out_size, void* d_ws, size_t ws_size,
                              hipStream_t stream) {
    const float* feats = (const float*)d_in[0];
    const int*   eidx  = (const int*)d_in[1];

    const int E = in_sizes[1] / 2;          // 320000
    const int N = in_sizes[0] / D_FEAT;     // 10000

    const int* src = eidx;       // edge_index row 0
    const int* dst = eidx + E;   // edge_index row 1

    float* seg_sum = (float*)d_ws;          // [N*PAD] padded, 64B per node
    float* out     = (float*)d_out;         // [E]

    // zero the used slots of the padded seg_sum
    {
        dim3 blk(256);
        dim3 grd((N + 255) / 256);
        zero_kernel<<<grd, blk, 0, stream>>>(seg_sum, N);
    }
    // Kernel A: 8 lanes/edge, 256 threads/block -> 32 edges/block
    {
        dim3 blk(256);
        dim3 grd((E + 31) / 32);
        edge_eval_kernel<<<grd, blk, 0, stream>>>(feats, src, dst, seg_sum, out, E);
    }
    // Divide pass: 4 edges/thread
    {
        int E4 = E >> 2;
        if (E4 > 0) {
            dim3 blk(256);
            dim3 grd((E4 + 255) / 256);
            edge_div_kernel<<<grd, blk, 0, stream>>>(dst, seg_sum, out, E4);
        }
        if (E & 3) {
            int start = E4 << 2;
            dim3 blk(64);
            dim3 grd(1);
            edge_div_tail_kernel<<<grd, blk, 0, stream>>>(dst, seg_sum, out, start, E);
        }
    }
}